// Round 4
// baseline (436.857 us; speedup 1.0000x reference)
//
#include <hip/hip_runtime.h>

#define H 64
#define FN 5
#define EPB 4096        // edges per scatter block
#define BSHIFT 8        // bucket = dst >> 8 (256 nodes per bucket)
#define CAP2 4864       // per-bucket edge staging (mean 4096, +12 sigma)

typedef _Float16 half4 __attribute__((ext_vector_type(4)));
typedef _Float16 half8 __attribute__((ext_vector_type(8)));
typedef float    float8v __attribute__((ext_vector_type(8)));

// ================= CSR build (2 big kernels + 1 tiny scan) =================
__global__ void k_bscatter2(const int* __restrict__ src, const int* __restrict__ dst,
                            int* __restrict__ lofs_g, int* __restrict__ bcounts,
                            int* __restrict__ binned, int nE, int nbB) {
    __shared__ int lh[512], lpos[512], lcur[512], tmp[256];
    __shared__ int stage[EPB];             // 16 KB
    int t = threadIdx.x;
    int e0 = blockIdx.x * EPB;
    int es[16], ed[16];
    lh[t] = 0; lh[t + 256] = 0;
    __syncthreads();
#pragma unroll
    for (int i = 0; i < 16; ++i) {
        int e = e0 + i * 256 + t;
        bool v = e < nE;
        es[i] = v ? src[e] : 0;
        ed[i] = v ? dst[e] : -1;
        if (v) atomicAdd(&lh[ed[i] >> BSHIFT], 1);
    }
    __syncthreads();
    int a0 = lh[2 * t], a1 = lh[2 * t + 1];
    tmp[t] = a0 + a1;
    __syncthreads();
    for (int s = 1; s < 256; s <<= 1) {
        int a = (t >= s) ? tmp[t - s] : 0;
        __syncthreads();
        tmp[t] += a;
        __syncthreads();
    }
    int ex = tmp[t] - (a0 + a1);
    lpos[2 * t] = ex;
    lpos[2 * t + 1] = ex + a0;
    __syncthreads();
    lcur[t] = lpos[t]; lcur[t + 256] = lpos[t + 256];
    size_t row = (size_t)blockIdx.x * (nbB + 1);
    for (int b = t; b <= nbB; b += 256) lofs_g[row + b] = lpos[b];
    for (int b = t; b < nbB; b += 256) if (lh[b]) atomicAdd(&bcounts[b], lh[b]);
    __syncthreads();
#pragma unroll
    for (int i = 0; i < 16; ++i) {
        if (ed[i] >= 0) {
            int b = ed[i] >> BSHIFT;
            int p = atomicAdd(&lcur[b], 1);
            stage[p] = es[i] | ((ed[i] & 255) << 17);
        }
    }
    __syncthreads();
    int total = lpos[nbB];
    for (int j = t; j < total; j += 256) binned[e0 + j] = stage[j];   // coalesced
}

__global__ void k_bscan2(const int* __restrict__ bcounts, int* __restrict__ bbase, int nbB) {
    __shared__ int tmp[512];
    int t = threadIdx.x;
    int v = (t < nbB) ? bcounts[t] : 0;
    tmp[t] = v;
    __syncthreads();
    for (int s = 1; s < 512; s <<= 1) {
        int a = (t >= s) ? tmp[t - s] : 0;
        __syncthreads();
        tmp[t] += a;
        __syncthreads();
    }
    if (t < nbB) bbase[t + 1] = tmp[t];
    if (t == 0) bbase[0] = 0;
}

__global__ void k_bcsr2(const int* __restrict__ binned, const int* __restrict__ lofs_g,
                        const int* __restrict__ bbase, int* __restrict__ row_ptr,
                        int* __restrict__ csr_src, float* __restrict__ dinv,
                        int n, int nE, int nbE, int nbB) {
    __shared__ int len_s[512], start_s[512], roff[512], tmp[256];
    __shared__ int deg[256], st[256], cur[256];
    __shared__ int lbuf[CAP2];      // 19 KB
    __shared__ int stage2[CAP2];    // 19 KB
    int t = threadIdx.x;
    int B = blockIdx.x;
    int node0 = B << BSHIFT;
    int nn = min(256, n - node0);
    len_s[t] = 0; len_s[t + 256] = 0;
    __syncthreads();
    for (int sb = t; sb < nbE; sb += 256) {
        size_t row = (size_t)sb * (nbB + 1);
        int o0 = lofs_g[row + B], o1 = lofs_g[row + B + 1];
        len_s[sb] = o1 - o0;
        start_s[sb] = sb * EPB + o0;
    }
    __syncthreads();
    int a0 = len_s[2 * t], a1 = len_s[2 * t + 1];
    tmp[t] = a0 + a1;
    __syncthreads();
    for (int s = 1; s < 256; s <<= 1) {
        int a = (t >= s) ? tmp[t - s] : 0;
        __syncthreads();
        tmp[t] += a;
        __syncthreads();
    }
    int ex = tmp[t] - (a0 + a1);
    roff[2 * t] = ex;
    roff[2 * t + 1] = ex + a0;
    __syncthreads();
    int total = min(roff[511] + len_s[511], CAP2);
    for (int sb = t; sb < nbE; sb += 256) {
        int s0 = start_s[sb], ln = len_s[sb], d0 = roff[sb];
        for (int k = 0; k < ln; ++k) {
            int d = d0 + k;
            if (d < CAP2) lbuf[d] = binned[s0 + k];
        }
    }
    deg[t] = 0;
    __syncthreads();
    for (int i = t; i < total; i += 256) atomicAdd(&deg[(lbuf[i] >> 17) & 255], 1);
    __syncthreads();
    tmp[t] = deg[t];
    __syncthreads();
    for (int s = 1; s < 256; s <<= 1) {
        int a = (t >= s) ? tmp[t - s] : 0;
        __syncthreads();
        tmp[t] += a;
        __syncthreads();
    }
    st[t] = tmp[t] - deg[t];
    cur[t] = st[t];
    __syncthreads();
    int base = bbase[B];
    if (t < nn) {
        row_ptr[node0 + t] = base + st[t];
        dinv[node0 + t] = 1.0f / sqrtf((float)deg[t] + 1.0f);
    }
    if (B == 0 && t == 0) row_ptr[n] = nE;
    for (int i = t; i < total; i += 256) {
        int p0 = lbuf[i];
        int p = atomicAdd(&cur[(p0 >> 17) & 255], 1);
        int sv = p0 & 0x1FFFF;
        if (p < CAP2) stage2[p] = sv;
        else csr_src[base + p] = sv;
    }
    __syncthreads();
    for (int i = t; i < total; i += 256) csr_src[base + i] = stage2[i];
}

// ================= encoder: g0 = fp16( dinv * relu(x@Wn+bn) ) =================
__global__ void k_enc(const float* __restrict__ x, const float* __restrict__ Wn,
                      const float* __restrict__ bn, const float* __restrict__ dinv,
                      _Float16* __restrict__ g0, int n) {
    int tid = blockIdx.x * 256 + threadIdx.x;
    int node = tid >> 6, ch = tid & 63;
    if (node >= n) return;
    float acc = bn[ch];
#pragma unroll
    for (int k = 0; k < FN; ++k)
        acc += x[(size_t)node * FN + k] * Wn[k * H + ch];
    g0[(size_t)node * H + ch] = (_Float16)(fmaxf(acc, 0.f) * dinv[node]);
}

#define CONSUME8(ACC, V) { _Pragma("unroll") \
    for (int k = 0; k < 8; ++k) ACC[k] += (float)V[k]; }

#define WB(ACCX, RX) { int nodeX = base + RX; float o[8]; \
    if (nodeX < n) { \
        half8 s = *(const half8*)(gin + (size_t)nodeX * H + c8); \
        float d = dv_s[RX]; \
        _Pragma("unroll") for (int k = 0; k < 8; ++k) o[k] = (ACCX[k] + (float)s[k]) * d; \
    } else { \
        _Pragma("unroll") for (int k = 0; k < 8; ++k) o[k] = 0.f; \
    } \
    *(float4*)&As[RX * 68 + c8]     = make_float4(o[0], o[1], o[2], o[3]); \
    *(float4*)&As[RX * 68 + c8 + 4] = make_float4(o[4], o[5], o[6], o[7]); }

// ================= fused layer: quad-node gather, pipelined index loads =====
// 64 nodes/block, 256 threads. Wave w handles node quads
// (rA=it*16+w, rB=rA+4, rC=rA+8, rD=rA+12), it=0..3 — FOUR independent
// idx->row gather chains per wave (double round 3's two), so ~4 scattered
// 8-row loads are in flight per wave instead of 2. Index loads stay one
// group ahead per stream (L1-hot csr_src slab); tail indices prefetched.
__global__ void k_layer(const _Float16* __restrict__ gin, const int* __restrict__ csr_src,
                        const int* __restrict__ row_ptr, const float* __restrict__ dinv,
                        const float* __restrict__ W, const float* __restrict__ bias,
                        _Float16* __restrict__ gout, float* __restrict__ hout,
                        int n, int last) {
    __shared__ float As[64 * 68];
    __shared__ int rp_s[65];
    __shared__ float dv_s[64];
    int t = threadIdx.x;
    int wave = t >> 6, lane = t & 63;
    int base = blockIdx.x * 64;
    if (t < 65) rp_s[t] = row_ptr[min(base + t, n)];
    if (t >= 128 && t < 192) {
        int nd = base + (t - 128);
        dv_s[t - 128] = (nd < n) ? dinv[nd] : 0.f;
    }
    __syncthreads();

    int c8 = (lane >> 3) * 8;
    int slot = lane & 7;
    for (int it = 0; it < 4; ++it) {
        int rA = it * 16 + wave, rB = rA + 4, rC = rA + 8, rD = rA + 12;
        float8v accA = 0.f, accB = 0.f, accC = 0.f, accD = 0.f;
        int iA = rp_s[rA], eA = rp_s[rA + 1];
        int iB = rp_s[rB], eB = rp_s[rB + 1];
        int iC = rp_s[rC], eC = rp_s[rC + 1];
        int iD = rp_s[rD], eD = rp_s[rD + 1];
        int cA = (eA - iA) >> 3, cB = (eB - iB) >> 3;
        int cC = (eC - iC) >> 3, cD = (eD - iD) >> 3;
        int tbA = iA + (cA << 3), tbB = iB + (cB << 3);
        int tbC = iC + (cC << 3), tbD = iD + (cD << 3);
        bool tvA = (tbA + slot < eA), tvB = (tbB + slot < eB);
        bool tvC = (tbC + slot < eC), tvD = (tbD + slot < eD);
        int xA = 0, xB = 0, xC = 0, xD = 0;
        int txA = 0, txB = 0, txC = 0, txD = 0;
        if (cA) xA = csr_src[iA + slot];
        if (cB) xB = csr_src[iB + slot];
        if (cC) xC = csr_src[iC + slot];
        if (cD) xD = csr_src[iD + slot];
        if (tvA) txA = csr_src[tbA + slot];
        if (tvB) txB = csr_src[tbB + slot];
        if (tvC) txC = csr_src[tbC + slot];
        if (tvD) txD = csr_src[tbD + slot];
        while (cA && cB && cC && cD) {
            half8 vA = *(const half8*)(gin + (size_t)xA * H + c8);
            half8 vB = *(const half8*)(gin + (size_t)xB * H + c8);
            half8 vC = *(const half8*)(gin + (size_t)xC * H + c8);
            half8 vD = *(const half8*)(gin + (size_t)xD * H + c8);
            iA += 8; iB += 8; iC += 8; iD += 8;
            --cA; --cB; --cC; --cD;
            if (cA) xA = csr_src[iA + slot];
            if (cB) xB = csr_src[iB + slot];
            if (cC) xC = csr_src[iC + slot];
            if (cD) xD = csr_src[iD + slot];
#pragma unroll
            for (int k = 0; k < 8; ++k) {
                accA[k] += (float)vA[k]; accB[k] += (float)vB[k];
                accC[k] += (float)vC[k]; accD[k] += (float)vD[k];
            }
        }
        while (cA && cB) {
            half8 vA = *(const half8*)(gin + (size_t)xA * H + c8);
            half8 vB = *(const half8*)(gin + (size_t)xB * H + c8);
            iA += 8; iB += 8; --cA; --cB;
            if (cA) xA = csr_src[iA + slot];
            if (cB) xB = csr_src[iB + slot];
#pragma unroll
            for (int k = 0; k < 8; ++k) { accA[k] += (float)vA[k]; accB[k] += (float)vB[k]; }
        }
        while (cC && cD) {
            half8 vC = *(const half8*)(gin + (size_t)xC * H + c8);
            half8 vD = *(const half8*)(gin + (size_t)xD * H + c8);
            iC += 8; iD += 8; --cC; --cD;
            if (cC) xC = csr_src[iC + slot];
            if (cD) xD = csr_src[iD + slot];
#pragma unroll
            for (int k = 0; k < 8; ++k) { accC[k] += (float)vC[k]; accD[k] += (float)vD[k]; }
        }
        while (cA) {
            half8 vA = *(const half8*)(gin + (size_t)xA * H + c8);
            iA += 8; --cA;
            if (cA) xA = csr_src[iA + slot];
            CONSUME8(accA, vA)
        }
        while (cB) {
            half8 vB = *(const half8*)(gin + (size_t)xB * H + c8);
            iB += 8; --cB;
            if (cB) xB = csr_src[iB + slot];
            CONSUME8(accB, vB)
        }
        while (cC) {
            half8 vC = *(const half8*)(gin + (size_t)xC * H + c8);
            iC += 8; --cC;
            if (cC) xC = csr_src[iC + slot];
            CONSUME8(accC, vC)
        }
        while (cD) {
            half8 vD = *(const half8*)(gin + (size_t)xD * H + c8);
            iD += 8; --cD;
            if (cD) xD = csr_src[iD + slot];
            CONSUME8(accD, vD)
        }
        if (tvA) { half8 v = *(const half8*)(gin + (size_t)txA * H + c8); CONSUME8(accA, v) }
        if (tvB) { half8 v = *(const half8*)(gin + (size_t)txB * H + c8); CONSUME8(accB, v) }
        if (tvC) { half8 v = *(const half8*)(gin + (size_t)txC * H + c8); CONSUME8(accC, v) }
        if (tvD) { half8 v = *(const half8*)(gin + (size_t)txD * H + c8); CONSUME8(accD, v) }
        // four independent reduce chains, interleaved
#pragma unroll
        for (int m = 1; m <= 4; m <<= 1) {
#pragma unroll
            for (int k = 0; k < 8; ++k) {
                accA[k] += __shfl_xor(accA[k], m, 64);
                accB[k] += __shfl_xor(accB[k], m, 64);
                accC[k] += __shfl_xor(accC[k], m, 64);
                accD[k] += __shfl_xor(accD[k], m, 64);
            }
        }
        if (slot == 0) {
            WB(accA, rA)
            WB(accB, rB)
            WB(accC, rC)
            WB(accD, rD)
        }
    }
    __syncthreads();

    // phase 2: 4x4 tile GEMM, W from global (L1-hot)
    int tx = t & 15, ty = t >> 4;
    int c0 = tx * 4;
    const float* a0 = As + (ty * 4 + 0) * 68;
    const float* a1 = As + (ty * 4 + 1) * 68;
    const float* a2 = As + (ty * 4 + 2) * 68;
    const float* a3 = As + (ty * 4 + 3) * 68;
    float4 acc0 = make_float4(0.f, 0.f, 0.f, 0.f);
    float4 acc1 = acc0, acc2 = acc0, acc3 = acc0;
#pragma unroll 16
    for (int k = 0; k < H; ++k) {
        float4 w = *(const float4*)(W + k * H + c0);
        float v0 = a0[k], v1 = a1[k], v2 = a2[k], v3 = a3[k];
        acc0.x += v0 * w.x; acc0.y += v0 * w.y; acc0.z += v0 * w.z; acc0.w += v0 * w.w;
        acc1.x += v1 * w.x; acc1.y += v1 * w.y; acc1.z += v1 * w.z; acc1.w += v1 * w.w;
        acc2.x += v2 * w.x; acc2.y += v2 * w.y; acc2.z += v2 * w.z; acc2.w += v2 * w.w;
        acc3.x += v3 * w.x; acc3.y += v3 * w.y; acc3.z += v3 * w.z; acc3.w += v3 * w.w;
    }
    float4 b = *(const float4*)(bias + c0);
    float4 accs[4] = {acc0, acc1, acc2, acc3};
#pragma unroll
    for (int rr = 0; rr < 4; ++rr) {
        int r = ty * 4 + rr;
        int row = base + r;
        if (row < n) {
            float4 o;
            o.x = fmaxf(accs[rr].x + b.x, 0.f);
            o.y = fmaxf(accs[rr].y + b.y, 0.f);
            o.z = fmaxf(accs[rr].z + b.z, 0.f);
            o.w = fmaxf(accs[rr].w + b.w, 0.f);
            if (last) {
                *(float4*)(hout + (size_t)row * H + c0) = o;
            } else {
                float d = dv_s[r];
                half4 hh;
                hh.x = (_Float16)(o.x * d);
                hh.y = (_Float16)(o.y * d);
                hh.z = (_Float16)(o.z * d);
                hh.w = (_Float16)(o.w * d);
                *(half4*)(gout + (size_t)row * H + c0) = hh;
            }
        }
    }
}

// ================= heads (lane = node) =================
__global__ void k_heads(const float* __restrict__ h,
                        const float* __restrict__ Wd1, const float* __restrict__ bd1,
                        const float* __restrict__ Wd2, const float* __restrict__ bd2,
                        const float* __restrict__ Wi1, const float* __restrict__ bi1,
                        const float* __restrict__ Wi2, const float* __restrict__ bi2,
                        float* __restrict__ out, int n) {
    __shared__ float hs[64 * 65];
    int lane = threadIdx.x;          // blockDim = 64
    int base = blockIdx.x * 64;
    for (int r = 0; r < 64; ++r) {
        int row = base + r;
        hs[r * 65 + lane] = (row < n) ? h[(size_t)row * H + lane] : 0.f;
    }
    __syncthreads();

    float accd[32], acci[32];
#pragma unroll
    for (int j = 0; j < 32; ++j) { accd[j] = bd1[j]; acci[j] = bi1[j]; }
    for (int k = 0; k < H; ++k) {
        float hk = hs[lane * 65 + k];
#pragma unroll
        for (int j = 0; j < 32; ++j) {
            accd[j] += hk * Wd1[k * 32 + j];
            acci[j] += hk * Wi1[k * 32 + j];
        }
    }
    float demand = bd2[0], inventory = bi2[0];
#pragma unroll
    for (int j = 0; j < 32; ++j) {
        demand    += fmaxf(accd[j], 0.f) * Wd2[j];
        inventory += fmaxf(acci[j], 0.f) * Wi2[j];
    }
    int node = base + lane;
    if (node < n) {
        out[node] = demand;
        out[n + node] = inventory;
    }
}

extern "C" void kernel_launch(void* const* d_in, const int* in_sizes, int n_in,
                              void* d_out, int out_size, void* d_ws, size_t ws_size,
                              hipStream_t stream) {
    const float* x   = (const float*)d_in[0];
    const int*   ei  = (const int*)  d_in[1];
    // d_in[2] = edge_attr, d_in[5] = We, d_in[6] = be : dead code in reference.
    const float* Wn  = (const float*)d_in[3];
    const float* bn  = (const float*)d_in[4];
    const float* Wc  = (const float*)d_in[7];   // [3,64,64]
    const float* bc  = (const float*)d_in[8];   // [3,64]
    const float* Wd1 = (const float*)d_in[9];
    const float* bd1 = (const float*)d_in[10];
    const float* Wd2 = (const float*)d_in[11];
    const float* bd2 = (const float*)d_in[12];
    const float* Wi1 = (const float*)d_in[13];
    const float* bi1 = (const float*)d_in[14];
    const float* Wi2 = (const float*)d_in[15];
    const float* bi2 = (const float*)d_in[16];

    const int n  = in_sizes[0] / FN;   // 100000
    const int nE = in_sizes[1] / 2;    // 1600000
    const int* src = ei;
    const int* dst = ei + nE;

    const int nbE = (nE + EPB - 1) / EPB;       // 391 scatter blocks
    const int nbB = (n + 255) >> BSHIFT;        // 391 buckets
    const int nbL = (n + 63) / 64;              // 1563

    char* w = (char*)d_ws;
    int* binned    = (int*)w;   w += (size_t)nbE * EPB * 4;
    int* csr_src   = (int*)w;   w += (size_t)nE * 4;
    int* row_ptr   = (int*)w;   w += (size_t)(n + 4) * 4;
    float* dinv    = (float*)w; w += (size_t)n * 4;
    int* lofs      = (int*)w;   w += (size_t)nbE * (nbB + 1) * 4;
    int* bcounts   = (int*)w;   w += 512 * 4;
    int* bbase     = (int*)w;   w += 516 * 4;
    float* hbuf    = (float*)w; w += (size_t)n * H * 4;
    _Float16* gA   = (_Float16*)w; w += (size_t)n * H * 2;
    _Float16* gB   = (_Float16*)w; w += (size_t)n * H * 2;

    hipMemsetAsync(bcounts, 0, 512 * 4, stream);

    k_bscatter2<<<nbE, 256, 0, stream>>>(src, dst, lofs, bcounts, binned, nE, nbB);
    k_bscan2   <<<1,   512, 0, stream>>>(bcounts, bbase, nbB);
    k_bcsr2    <<<nbB, 256, 0, stream>>>(binned, lofs, bbase, row_ptr, csr_src,
                                         dinv, n, nE, nbE, nbB);

    k_enc<<<((size_t)n * 64 + 255) / 256, 256, 0, stream>>>(x, Wn, bn, dinv, gA, n);

    k_layer<<<nbL, 256, 0, stream>>>(gA, csr_src, row_ptr, dinv, Wc,
                                     bc, gB, hbuf, n, 0);
    k_layer<<<nbL, 256, 0, stream>>>(gB, csr_src, row_ptr, dinv, Wc + (size_t)H * H,
                                     bc + H, gA, hbuf, n, 0);
    k_layer<<<nbL, 256, 0, stream>>>(gA, csr_src, row_ptr, dinv, Wc + (size_t)2 * H * H,
                                     bc + 2 * H, gB, hbuf, n, 1);

    k_heads<<<(n + 63) / 64, 64, 0, stream>>>(hbuf, Wd1, bd1, Wd2, bd2,
                                              Wi1, bi1, Wi2, bi2, (float*)d_out, n);
}

// Round 5
// 400.218 us; speedup vs baseline: 1.0915x; 1.0915x over previous
//
#include <hip/hip_runtime.h>

#define H 64
#define FN 5
#define EPB 4096        // edges per scatter block
#define BSHIFT 8        // bucket = dst >> 8 (256 nodes per bucket)
#define CAP2 4864       // per-bucket edge staging (mean 4096, +12 sigma)

typedef _Float16 half4 __attribute__((ext_vector_type(4)));
typedef _Float16 half8 __attribute__((ext_vector_type(8)));
typedef float    float8v __attribute__((ext_vector_type(8)));

// ================= CSR build (2 big kernels + 1 tiny scan) =================
__global__ void k_bscatter2(const int* __restrict__ src, const int* __restrict__ dst,
                            int* __restrict__ lofs_g, int* __restrict__ bcounts,
                            int* __restrict__ binned, int nE, int nbB) {
    __shared__ int lh[512], lpos[512], lcur[512], tmp[256];
    __shared__ int stage[EPB];             // 16 KB
    int t = threadIdx.x;
    int e0 = blockIdx.x * EPB;
    int es[16], ed[16];
    lh[t] = 0; lh[t + 256] = 0;
    __syncthreads();
#pragma unroll
    for (int i = 0; i < 16; ++i) {
        int e = e0 + i * 256 + t;
        bool v = e < nE;
        es[i] = v ? src[e] : 0;
        ed[i] = v ? dst[e] : -1;
        if (v) atomicAdd(&lh[ed[i] >> BSHIFT], 1);
    }
    __syncthreads();
    int a0 = lh[2 * t], a1 = lh[2 * t + 1];
    tmp[t] = a0 + a1;
    __syncthreads();
    for (int s = 1; s < 256; s <<= 1) {
        int a = (t >= s) ? tmp[t - s] : 0;
        __syncthreads();
        tmp[t] += a;
        __syncthreads();
    }
    int ex = tmp[t] - (a0 + a1);
    lpos[2 * t] = ex;
    lpos[2 * t + 1] = ex + a0;
    __syncthreads();
    lcur[t] = lpos[t]; lcur[t + 256] = lpos[t + 256];
    size_t row = (size_t)blockIdx.x * (nbB + 1);
    for (int b = t; b <= nbB; b += 256) lofs_g[row + b] = lpos[b];
    for (int b = t; b < nbB; b += 256) if (lh[b]) atomicAdd(&bcounts[b], lh[b]);
    __syncthreads();
#pragma unroll
    for (int i = 0; i < 16; ++i) {
        if (ed[i] >= 0) {
            int b = ed[i] >> BSHIFT;
            int p = atomicAdd(&lcur[b], 1);
            stage[p] = es[i] | ((ed[i] & 255) << 17);
        }
    }
    __syncthreads();
    int total = lpos[nbB];
    for (int j = t; j < total; j += 256) binned[e0 + j] = stage[j];   // coalesced
}

__global__ void k_bscan2(const int* __restrict__ bcounts, int* __restrict__ bbase, int nbB) {
    __shared__ int tmp[512];
    int t = threadIdx.x;
    int v = (t < nbB) ? bcounts[t] : 0;
    tmp[t] = v;
    __syncthreads();
    for (int s = 1; s < 512; s <<= 1) {
        int a = (t >= s) ? tmp[t - s] : 0;
        __syncthreads();
        tmp[t] += a;
        __syncthreads();
    }
    if (t < nbB) bbase[t + 1] = tmp[t];
    if (t == 0) bbase[0] = 0;
}

__global__ void k_bcsr2(const int* __restrict__ binned, const int* __restrict__ lofs_g,
                        const int* __restrict__ bbase, int* __restrict__ row_ptr,
                        int* __restrict__ csr_src, float* __restrict__ dinv,
                        int n, int nE, int nbE, int nbB) {
    __shared__ int len_s[512], start_s[512], roff[512], tmp[256];
    __shared__ int deg[256], st[256], cur[256];
    __shared__ int lbuf[CAP2];      // 19 KB
    __shared__ int stage2[CAP2];    // 19 KB
    int t = threadIdx.x;
    int B = blockIdx.x;
    int node0 = B << BSHIFT;
    int nn = min(256, n - node0);
    len_s[t] = 0; len_s[t + 256] = 0;
    __syncthreads();
    for (int sb = t; sb < nbE; sb += 256) {
        size_t row = (size_t)sb * (nbB + 1);
        int o0 = lofs_g[row + B], o1 = lofs_g[row + B + 1];
        len_s[sb] = o1 - o0;
        start_s[sb] = sb * EPB + o0;
    }
    __syncthreads();
    int a0 = len_s[2 * t], a1 = len_s[2 * t + 1];
    tmp[t] = a0 + a1;
    __syncthreads();
    for (int s = 1; s < 256; s <<= 1) {
        int a = (t >= s) ? tmp[t - s] : 0;
        __syncthreads();
        tmp[t] += a;
        __syncthreads();
    }
    int ex = tmp[t] - (a0 + a1);
    roff[2 * t] = ex;
    roff[2 * t + 1] = ex + a0;
    __syncthreads();
    int total = min(roff[511] + len_s[511], CAP2);
    for (int sb = t; sb < nbE; sb += 256) {
        int s0 = start_s[sb], ln = len_s[sb], d0 = roff[sb];
        for (int k = 0; k < ln; ++k) {
            int d = d0 + k;
            if (d < CAP2) lbuf[d] = binned[s0 + k];
        }
    }
    deg[t] = 0;
    __syncthreads();
    for (int i = t; i < total; i += 256) atomicAdd(&deg[(lbuf[i] >> 17) & 255], 1);
    __syncthreads();
    tmp[t] = deg[t];
    __syncthreads();
    for (int s = 1; s < 256; s <<= 1) {
        int a = (t >= s) ? tmp[t - s] : 0;
        __syncthreads();
        tmp[t] += a;
        __syncthreads();
    }
    st[t] = tmp[t] - deg[t];
    cur[t] = st[t];
    __syncthreads();
    int base = bbase[B];
    if (t < nn) {
        row_ptr[node0 + t] = base + st[t];
        dinv[node0 + t] = 1.0f / sqrtf((float)deg[t] + 1.0f);
    }
    if (B == 0 && t == 0) row_ptr[n] = nE;
    for (int i = t; i < total; i += 256) {
        int p0 = lbuf[i];
        int p = atomicAdd(&cur[(p0 >> 17) & 255], 1);
        int sv = p0 & 0x1FFFF;
        if (p < CAP2) stage2[p] = sv;
        else csr_src[base + p] = sv;
    }
    __syncthreads();
    for (int i = t; i < total; i += 256) csr_src[base + i] = stage2[i];
}

// ================= encoder: g0 = fp16( dinv * relu(x@Wn+bn) ) =================
__global__ void k_enc(const float* __restrict__ x, const float* __restrict__ Wn,
                      const float* __restrict__ bn, const float* __restrict__ dinv,
                      _Float16* __restrict__ g0, int n) {
    int tid = blockIdx.x * 256 + threadIdx.x;
    int node = tid >> 6, ch = tid & 63;
    if (node >= n) return;
    float acc = bn[ch];
#pragma unroll
    for (int k = 0; k < FN; ++k)
        acc += x[(size_t)node * FN + k] * Wn[k * H + ch];
    g0[(size_t)node * H + ch] = (_Float16)(fmaxf(acc, 0.f) * dinv[node]);
}

#define FMA4(ACC, S, WV) ACC.x += (S)*(WV).x; ACC.y += (S)*(WV).y; \
                         ACC.z += (S)*(WV).z; ACC.w += (S)*(WV).w;

// Shared phase-1 gather + phase-2 GEMM (round-3 structure, 36 VGPR proven).
// Result rows (post-bias, post-relu, fp32) land in As[r*68 + c] and each
// thread returns its 4x4 accs via os[]; caller decides the epilogue.
__device__ __forceinline__ void layer_body(
        const _Float16* __restrict__ gin, const int* __restrict__ csr_src,
        const float* __restrict__ W, const float* __restrict__ bias,
        float* As, int* rp_s, float* dv_s, const int* __restrict__ row_ptr,
        const float* __restrict__ dinv, int n, int base, int t,
        float4* os /*[4]*/) {
    int wave = t >> 6, lane = t & 63;
    if (t < 65) rp_s[t] = row_ptr[min(base + t, n)];
    if (t >= 128 && t < 192) {
        int nd = base + (t - 128);
        dv_s[t - 128] = (nd < n) ? dinv[nd] : 0.f;
    }
    __syncthreads();

    int c8 = (lane >> 3) * 8;
    int slot = lane & 7;
    for (int it = 0; it < 8; ++it) {
        int rA = it * 8 + wave, rB = rA + 4;
        int nodeA = base + rA, nodeB = base + rB;
        float8v accA = 0.f, accB = 0.f;
        int iA = rp_s[rA], eA = rp_s[rA + 1];
        int iB = rp_s[rB], eB = rp_s[rB + 1];
        int cA = (eA - iA) >> 3, cB = (eB - iB) >> 3;   // full 8-edge groups
        int xA = 0, xB = 0, txA = 0, txB = 0;
        int tbA = iA + (cA << 3), tbB = iB + (cB << 3);
        bool tvA = (tbA + slot < eA), tvB = (tbB + slot < eB);
        if (cA) xA = csr_src[iA + slot];
        if (cB) xB = csr_src[iB + slot];
        if (tvA) txA = csr_src[tbA + slot];
        if (tvB) txB = csr_src[tbB + slot];
        while (cA && cB) {
            half8 vA = *(const half8*)(gin + (size_t)xA * H + c8);
            half8 vB = *(const half8*)(gin + (size_t)xB * H + c8);
            iA += 8; iB += 8; --cA; --cB;
            if (cA) xA = csr_src[iA + slot];      // issued before vA/vB consumed
            if (cB) xB = csr_src[iB + slot];
#pragma unroll
            for (int k = 0; k < 8; ++k) { accA[k] += (float)vA[k]; accB[k] += (float)vB[k]; }
        }
        while (cA) {
            half8 vA = *(const half8*)(gin + (size_t)xA * H + c8);
            iA += 8; --cA;
            if (cA) xA = csr_src[iA + slot];
#pragma unroll
            for (int k = 0; k < 8; ++k) accA[k] += (float)vA[k];
        }
        while (cB) {
            half8 vB = *(const half8*)(gin + (size_t)xB * H + c8);
            iB += 8; --cB;
            if (cB) xB = csr_src[iB + slot];
#pragma unroll
            for (int k = 0; k < 8; ++k) accB[k] += (float)vB[k];
        }
        if (tvA) {
            half8 vA = *(const half8*)(gin + (size_t)txA * H + c8);
#pragma unroll
            for (int k = 0; k < 8; ++k) accA[k] += (float)vA[k];
        }
        if (tvB) {
            half8 vB = *(const half8*)(gin + (size_t)txB * H + c8);
#pragma unroll
            for (int k = 0; k < 8; ++k) accB[k] += (float)vB[k];
        }
#pragma unroll
        for (int m = 1; m <= 4; m <<= 1) {
#pragma unroll
            for (int k = 0; k < 8; ++k) {
                accA[k] += __shfl_xor(accA[k], m, 64);
                accB[k] += __shfl_xor(accB[k], m, 64);
            }
        }
        if (slot == 0) {
            float oA[8], oB[8];
            if (nodeA < n) {
                half8 sA = *(const half8*)(gin + (size_t)nodeA * H + c8);
                float dA = dv_s[rA];
#pragma unroll
                for (int k = 0; k < 8; ++k) oA[k] = (accA[k] + (float)sA[k]) * dA;
            } else {
#pragma unroll
                for (int k = 0; k < 8; ++k) oA[k] = 0.f;
            }
            if (nodeB < n) {
                half8 sB = *(const half8*)(gin + (size_t)nodeB * H + c8);
                float dB = dv_s[rB];
#pragma unroll
                for (int k = 0; k < 8; ++k) oB[k] = (accB[k] + (float)sB[k]) * dB;
            } else {
#pragma unroll
                for (int k = 0; k < 8; ++k) oB[k] = 0.f;
            }
            *(float4*)&As[rA * 68 + c8]     = make_float4(oA[0], oA[1], oA[2], oA[3]);
            *(float4*)&As[rA * 68 + c8 + 4] = make_float4(oA[4], oA[5], oA[6], oA[7]);
            *(float4*)&As[rB * 68 + c8]     = make_float4(oB[0], oB[1], oB[2], oB[3]);
            *(float4*)&As[rB * 68 + c8 + 4] = make_float4(oB[4], oB[5], oB[6], oB[7]);
        }
    }
    __syncthreads();

    // phase 2: 4x4 tile GEMM, W from global (L1-hot)
    int tx = t & 15, ty = t >> 4;
    int c0 = tx * 4;
    const float* a0 = As + (ty * 4 + 0) * 68;
    const float* a1 = As + (ty * 4 + 1) * 68;
    const float* a2 = As + (ty * 4 + 2) * 68;
    const float* a3 = As + (ty * 4 + 3) * 68;
    float4 acc0 = make_float4(0.f, 0.f, 0.f, 0.f);
    float4 acc1 = acc0, acc2 = acc0, acc3 = acc0;
#pragma unroll 16
    for (int k = 0; k < H; ++k) {
        float4 w = *(const float4*)(W + k * H + c0);
        float v0 = a0[k], v1 = a1[k], v2 = a2[k], v3 = a3[k];
        acc0.x += v0 * w.x; acc0.y += v0 * w.y; acc0.z += v0 * w.z; acc0.w += v0 * w.w;
        acc1.x += v1 * w.x; acc1.y += v1 * w.y; acc1.z += v1 * w.z; acc1.w += v1 * w.w;
        acc2.x += v2 * w.x; acc2.y += v2 * w.y; acc2.z += v2 * w.z; acc2.w += v2 * w.w;
        acc3.x += v3 * w.x; acc3.y += v3 * w.y; acc3.z += v3 * w.z; acc3.w += v3 * w.w;
    }
    float4 b = *(const float4*)(bias + c0);
    float4 accs[4] = {acc0, acc1, acc2, acc3};
#pragma unroll
    for (int rr = 0; rr < 4; ++rr) {
        os[rr].x = fmaxf(accs[rr].x + b.x, 0.f);
        os[rr].y = fmaxf(accs[rr].y + b.y, 0.f);
        os[rr].z = fmaxf(accs[rr].z + b.z, 0.f);
        os[rr].w = fmaxf(accs[rr].w + b.w, 0.f);
    }
}

// ================= layers 1..L-1: write fp16 gout (round-3 proven, 36 VGPR) ==
__global__ void k_layer(const _Float16* __restrict__ gin, const int* __restrict__ csr_src,
                        const int* __restrict__ row_ptr, const float* __restrict__ dinv,
                        const float* __restrict__ W, const float* __restrict__ bias,
                        _Float16* __restrict__ gout, int n) {
    __shared__ float As[64 * 68];
    __shared__ int rp_s[65];
    __shared__ float dv_s[64];
    int t = threadIdx.x;
    int base = blockIdx.x * 64;
    float4 os[4];
    layer_body(gin, csr_src, W, bias, As, rp_s, dv_s, row_ptr, dinv, n, base, t, os);
    int tx = t & 15, ty = t >> 4;
    int c0 = tx * 4;
#pragma unroll
    for (int rr = 0; rr < 4; ++rr) {
        int r = ty * 4 + rr;
        int row = base + r;
        if (row < n) {
            float d = dv_s[r];
            half4 hh;
            hh.x = (_Float16)(os[rr].x * d);
            hh.y = (_Float16)(os[rr].y * d);
            hh.z = (_Float16)(os[rr].z * d);
            hh.w = (_Float16)(os[rr].w * d);
            *(half4*)(gout + (size_t)row * H + c0) = hh;
        }
    }
}

// ================= last layer: heads fused off the LDS h-tile ===============
// Separate kernel so the head epilogue's register demand does NOT bloat the
// other two layer dispatches (R2 lesson: shared kernel -> 64 VGPR everywhere).
__global__ void k_layer_last(const _Float16* __restrict__ gin, const int* __restrict__ csr_src,
                             const int* __restrict__ row_ptr, const float* __restrict__ dinv,
                             const float* __restrict__ W, const float* __restrict__ bias,
                             const float* __restrict__ Wd1, const float* __restrict__ bd1,
                             const float* __restrict__ Wd2, const float* __restrict__ bd2,
                             const float* __restrict__ Wi1, const float* __restrict__ bi1,
                             const float* __restrict__ Wi2, const float* __restrict__ bi2,
                             float* __restrict__ out, int n) {
    __shared__ float As[64 * 68];
    __shared__ int rp_s[65];
    __shared__ float dv_s[64];
    int t = threadIdx.x;
    int base = blockIdx.x * 64;
    float4 os[4];
    layer_body(gin, csr_src, W, bias, As, rp_s, dv_s, row_ptr, dinv, n, base, t, os);
    int tx = t & 15, ty = t >> 4;
    int c0 = tx * 4;
    __syncthreads();                       // all As reads done
#pragma unroll
    for (int rr = 0; rr < 4; ++rr)
        *(float4*)(As + (ty * 4 + rr) * 68 + c0) = os[rr];
    __syncthreads();
    // 4 threads per node, 8 hidden units each (verified in round 2)
    int nl = t >> 2, sub = t & 3, j0 = sub * 8;
    int node = base + nl;
    float4 ad0 = *(const float4*)(bd1 + j0);
    float4 ad1 = *(const float4*)(bd1 + j0 + 4);
    float4 ai0 = *(const float4*)(bi1 + j0);
    float4 ai1 = *(const float4*)(bi1 + j0 + 4);
    const float* hrow = As + nl * 68;
#pragma unroll 4
    for (int k = 0; k < H; ++k) {
        float hk = hrow[k];
        float4 wd0 = *(const float4*)(Wd1 + k * 32 + j0);
        float4 wd1v = *(const float4*)(Wd1 + k * 32 + j0 + 4);
        float4 wi0 = *(const float4*)(Wi1 + k * 32 + j0);
        float4 wi1v = *(const float4*)(Wi1 + k * 32 + j0 + 4);
        FMA4(ad0, hk, wd0) FMA4(ad1, hk, wd1v)
        FMA4(ai0, hk, wi0) FMA4(ai1, hk, wi1v)
    }
    float4 w2d0 = *(const float4*)(Wd2 + j0);
    float4 w2d1 = *(const float4*)(Wd2 + j0 + 4);
    float4 w2i0 = *(const float4*)(Wi2 + j0);
    float4 w2i1 = *(const float4*)(Wi2 + j0 + 4);
    float dp = fmaxf(ad0.x, 0.f) * w2d0.x + fmaxf(ad0.y, 0.f) * w2d0.y
             + fmaxf(ad0.z, 0.f) * w2d0.z + fmaxf(ad0.w, 0.f) * w2d0.w
             + fmaxf(ad1.x, 0.f) * w2d1.x + fmaxf(ad1.y, 0.f) * w2d1.y
             + fmaxf(ad1.z, 0.f) * w2d1.z + fmaxf(ad1.w, 0.f) * w2d1.w;
    float ip = fmaxf(ai0.x, 0.f) * w2i0.x + fmaxf(ai0.y, 0.f) * w2i0.y
             + fmaxf(ai0.z, 0.f) * w2i0.z + fmaxf(ai0.w, 0.f) * w2i0.w
             + fmaxf(ai1.x, 0.f) * w2i1.x + fmaxf(ai1.y, 0.f) * w2i1.y
             + fmaxf(ai1.z, 0.f) * w2i1.z + fmaxf(ai1.w, 0.f) * w2i1.w;
    dp += __shfl_xor(dp, 1, 64); dp += __shfl_xor(dp, 2, 64);
    ip += __shfl_xor(ip, 1, 64); ip += __shfl_xor(ip, 2, 64);
    if (sub == 0 && node < n) {
        out[node] = dp + bd2[0];
        out[n + node] = ip + bi2[0];
    }
}

extern "C" void kernel_launch(void* const* d_in, const int* in_sizes, int n_in,
                              void* d_out, int out_size, void* d_ws, size_t ws_size,
                              hipStream_t stream) {
    const float* x   = (const float*)d_in[0];
    const int*   ei  = (const int*)  d_in[1];
    // d_in[2] = edge_attr, d_in[5] = We, d_in[6] = be : dead code in reference.
    const float* Wn  = (const float*)d_in[3];
    const float* bn  = (const float*)d_in[4];
    const float* Wc  = (const float*)d_in[7];   // [3,64,64]
    const float* bc  = (const float*)d_in[8];   // [3,64]
    const float* Wd1 = (const float*)d_in[9];
    const float* bd1 = (const float*)d_in[10];
    const float* Wd2 = (const float*)d_in[11];
    const float* bd2 = (const float*)d_in[12];
    const float* Wi1 = (const float*)d_in[13];
    const float* bi1 = (const float*)d_in[14];
    const float* Wi2 = (const float*)d_in[15];
    const float* bi2 = (const float*)d_in[16];

    const int n  = in_sizes[0] / FN;   // 100000
    const int nE = in_sizes[1] / 2;    // 1600000
    const int* src = ei;
    const int* dst = ei + nE;

    const int nbE = (nE + EPB - 1) / EPB;       // 391 scatter blocks
    const int nbB = (n + 255) >> BSHIFT;        // 391 buckets
    const int nbL = (n + 63) / 64;              // 1563

    char* w = (char*)d_ws;
    int* binned    = (int*)w;   w += (size_t)nbE * EPB * 4;
    int* csr_src   = (int*)w;   w += (size_t)nE * 4;
    int* row_ptr   = (int*)w;   w += (size_t)(n + 4) * 4;
    float* dinv    = (float*)w; w += (size_t)n * 4;
    int* lofs      = (int*)w;   w += (size_t)nbE * (nbB + 1) * 4;
    int* bcounts   = (int*)w;   w += 512 * 4;
    int* bbase     = (int*)w;   w += 516 * 4;
    _Float16* gA   = (_Float16*)w; w += (size_t)n * H * 2;
    _Float16* gB   = (_Float16*)w; w += (size_t)n * H * 2;

    hipMemsetAsync(bcounts, 0, 512 * 4, stream);

    k_bscatter2<<<nbE, 256, 0, stream>>>(src, dst, lofs, bcounts, binned, nE, nbB);
    k_bscan2   <<<1,   512, 0, stream>>>(bcounts, bbase, nbB);
    k_bcsr2    <<<nbB, 256, 0, stream>>>(binned, lofs, bbase, row_ptr, csr_src,
                                         dinv, n, nE, nbE, nbB);

    k_enc<<<((size_t)n * 64 + 255) / 256, 256, 0, stream>>>(x, Wn, bn, dinv, gA, n);

    k_layer<<<nbL, 256, 0, stream>>>(gA, csr_src, row_ptr, dinv, Wc, bc, gB, n);
    k_layer<<<nbL, 256, 0, stream>>>(gB, csr_src, row_ptr, dinv, Wc + (size_t)H * H,
                                     bc + H, gA, n);
    k_layer_last<<<nbL, 256, 0, stream>>>(gA, csr_src, row_ptr, dinv,
                                          Wc + (size_t)2 * H * H, bc + 2 * H,
                                          Wd1, bd1, Wd2, bd2, Wi1, bi1, Wi2, bi2,
                                          (float*)d_out, n);
}

// Round 7
// 378.743 us; speedup vs baseline: 1.1534x; 1.0567x over previous
//
#include <hip/hip_runtime.h>

#define H 64
#define FN 5
#define EPB 4096        // edges per scatter block
#define BSHIFT 8        // bucket = dst >> 8 (256 nodes per bucket)
#define CAP2 4864       // per-bucket edge staging (mean 4096, +12 sigma)

typedef _Float16 half4 __attribute__((ext_vector_type(4)));
typedef _Float16 half8 __attribute__((ext_vector_type(8)));
typedef float    float8v __attribute__((ext_vector_type(8)));

// ================= CSR build (2 big kernels + 1 tiny scan) =================
// k_bscatter2: as before, but lofs is written TRANSPOSED (lofs_t[b][sb]) so
// k_bcsr2's per-bucket read becomes two coalesced rows instead of a 1564-B
// strided column walk.
__global__ void k_bscatter2(const int* __restrict__ src, const int* __restrict__ dst,
                            int* __restrict__ lofs_t, int* __restrict__ bcounts,
                            int* __restrict__ binned, int nE, int nbB, int nbE) {
    __shared__ int lh[512], lpos[512], lcur[512], tmp[256];
    __shared__ int stage[EPB];             // 16 KB
    int t = threadIdx.x;
    int e0 = blockIdx.x * EPB;
    int es[16], ed[16];
    lh[t] = 0; lh[t + 256] = 0;
    __syncthreads();
#pragma unroll
    for (int i = 0; i < 16; ++i) {
        int e = e0 + i * 256 + t;
        bool v = e < nE;
        es[i] = v ? src[e] : 0;
        ed[i] = v ? dst[e] : -1;
        if (v) atomicAdd(&lh[ed[i] >> BSHIFT], 1);
    }
    __syncthreads();
    int a0 = lh[2 * t], a1 = lh[2 * t + 1];
    tmp[t] = a0 + a1;
    __syncthreads();
    for (int s = 1; s < 256; s <<= 1) {
        int a = (t >= s) ? tmp[t - s] : 0;
        __syncthreads();
        tmp[t] += a;
        __syncthreads();
    }
    int ex = tmp[t] - (a0 + a1);
    lpos[2 * t] = ex;
    lpos[2 * t + 1] = ex + a0;
    __syncthreads();
    lcur[t] = lpos[t]; lcur[t + 256] = lpos[t + 256];
    // transposed offset write: lofs_t[b * nbE + block]
    for (int b = t; b <= nbB; b += 256) lofs_t[(size_t)b * nbE + blockIdx.x] = lpos[b];
    for (int b = t; b < nbB; b += 256) if (lh[b]) atomicAdd(&bcounts[b], lh[b]);
    __syncthreads();
#pragma unroll
    for (int i = 0; i < 16; ++i) {
        if (ed[i] >= 0) {
            int b = ed[i] >> BSHIFT;
            int p = atomicAdd(&lcur[b], 1);
            stage[p] = es[i] | ((ed[i] & 255) << 17);
        }
    }
    __syncthreads();
    int total = lpos[nbB];
    for (int j = t; j < total; j += 256) binned[e0 + j] = stage[j];   // coalesced
}

__global__ void k_bscan2(const int* __restrict__ bcounts, int* __restrict__ bbase, int nbB) {
    __shared__ int tmp[512];
    int t = threadIdx.x;
    int v = (t < nbB) ? bcounts[t] : 0;
    tmp[t] = v;
    __syncthreads();
    for (int s = 1; s < 512; s <<= 1) {
        int a = (t >= s) ? tmp[t - s] : 0;
        __syncthreads();
        tmp[t] += a;
        __syncthreads();
    }
    if (t < nbB) bbase[t + 1] = tmp[t];
    if (t == 0) bbase[0] = 0;
}

// k_bcsr2: coalesced transposed-lofs read; FLAT gather of the bucket's runs
// into lbuf via binary search over the run-offset prefix (all loads
// independent — no per-element global->LDS latency serialization).
__global__ void k_bcsr2(const int* __restrict__ binned, const int* __restrict__ lofs_t,
                        const int* __restrict__ bbase, int* __restrict__ row_ptr,
                        int* __restrict__ csr_src, float* __restrict__ dinv,
                        int n, int nE, int nbE, int nbB) {
    __shared__ int start_s[512], roff[513], tmp[256];
    __shared__ int deg[256], st[256], cur[256];
    __shared__ int lbuf[CAP2];      // 19 KB
    __shared__ int stage2[CAP2];    // 19 KB
    int t = threadIdx.x;
    int B = blockIdx.x;
    int node0 = B << BSHIFT;
    int nn = min(256, n - node0);
    // thread t owns scatter-blocks 2t, 2t+1 (adjacent pair for the scan)
    int s0i = 2 * t, s1i = 2 * t + 1;
    int a0 = 0, a1 = 0;
    if (s0i < nbE) {
        int o0 = lofs_t[B * nbE + s0i], o1 = lofs_t[(B + 1) * nbE + s0i];
        a0 = o1 - o0;
        start_s[s0i] = s0i * EPB + o0;
    } else start_s[s0i] = 0;
    if (s1i < nbE) {
        int o0 = lofs_t[B * nbE + s1i], o1 = lofs_t[(B + 1) * nbE + s1i];
        a1 = o1 - o0;
        start_s[s1i] = s1i * EPB + o0;
    } else start_s[s1i] = 0;
    tmp[t] = a0 + a1;
    __syncthreads();
    for (int s = 1; s < 256; s <<= 1) {
        int a = (t >= s) ? tmp[t - s] : 0;
        __syncthreads();
        tmp[t] += a;
        __syncthreads();
    }
    int ex = tmp[t] - (a0 + a1);
    roff[2 * t] = ex;
    roff[2 * t + 1] = ex + a0;
    if (t == 255) roff[512] = tmp[255];   // sentinel = block total
    __syncthreads();
    int total = min(roff[512], CAP2);
    // flat gather: element i -> run lo with roff[lo] <= i < roff[lo+1]
    for (int i = t; i < total; i += 256) {
        int lo = 0, hi = 512;
        while (hi - lo > 1) {
            int mid = (lo + hi) >> 1;
            if (roff[mid] <= i) lo = mid; else hi = mid;
        }
        lbuf[i] = binned[start_s[lo] + (i - roff[lo])];
    }
    deg[t] = 0;
    __syncthreads();
    for (int i = t; i < total; i += 256) atomicAdd(&deg[(lbuf[i] >> 17) & 255], 1);
    __syncthreads();
    tmp[t] = deg[t];
    __syncthreads();
    for (int s = 1; s < 256; s <<= 1) {
        int a = (t >= s) ? tmp[t - s] : 0;
        __syncthreads();
        tmp[t] += a;
        __syncthreads();
    }
    st[t] = tmp[t] - deg[t];
    cur[t] = st[t];
    __syncthreads();
    int base = bbase[B];
    if (t < nn) {
        row_ptr[node0 + t] = base + st[t];
        dinv[node0 + t] = 1.0f / sqrtf((float)deg[t] + 1.0f);
    }
    if (B == 0 && t == 0) row_ptr[n] = nE;
    for (int i = t; i < total; i += 256) {
        int p0 = lbuf[i];
        int p = atomicAdd(&cur[(p0 >> 17) & 255], 1);
        int sv = p0 & 0x1FFFF;
        if (p < CAP2) stage2[p] = sv;
        else csr_src[base + p] = sv;
    }
    __syncthreads();
    for (int i = t; i < total; i += 256) csr_src[base + i] = stage2[i];
}

// ================= encoder: g0 = fp16( dinv * relu(x@Wn+bn) ) =================
// 4 nodes/thread: grid 25000 -> 6250 blocks, Wn row hoisted to registers.
__global__ void k_enc(const float* __restrict__ x, const float* __restrict__ Wn,
                      const float* __restrict__ bn, const float* __restrict__ dinv,
                      _Float16* __restrict__ g0, int n) {
    int tid = blockIdx.x * 256 + threadIdx.x;
    int ch = threadIdx.x & 63;
    int node0 = (tid >> 6) * 4;
    if (node0 >= n) return;
    float wr[FN];
#pragma unroll
    for (int k = 0; k < FN; ++k) wr[k] = Wn[k * H + ch];
    float b = bn[ch];
#pragma unroll
    for (int j = 0; j < 4; ++j) {
        int node = node0 + j;
        if (node < n) {
            float acc = b;
#pragma unroll
            for (int k = 0; k < FN; ++k)
                acc += x[(size_t)node * FN + k] * wr[k];
            g0[(size_t)node * H + ch] = (_Float16)(fmaxf(acc, 0.f) * dinv[node]);
        }
    }
}

// ================= fused layer: dual-node gather, pipelined index loads =====
// (byte-identical to the 379.7 us round-3 kernel)
__global__ void k_layer(const _Float16* __restrict__ gin, const int* __restrict__ csr_src,
                        const int* __restrict__ row_ptr, const float* __restrict__ dinv,
                        const float* __restrict__ W, const float* __restrict__ bias,
                        _Float16* __restrict__ gout, float* __restrict__ hout,
                        int n, int last) {
    __shared__ float As[64 * 68];
    __shared__ int rp_s[65];
    __shared__ float dv_s[64];
    int t = threadIdx.x;
    int wave = t >> 6, lane = t & 63;
    int base = blockIdx.x * 64;
    if (t < 65) rp_s[t] = row_ptr[min(base + t, n)];
    if (t >= 128 && t < 192) {
        int nd = base + (t - 128);
        dv_s[t - 128] = (nd < n) ? dinv[nd] : 0.f;
    }
    __syncthreads();

    int c8 = (lane >> 3) * 8;
    int slot = lane & 7;
    for (int it = 0; it < 8; ++it) {
        int rA = it * 8 + wave, rB = rA + 4;
        int nodeA = base + rA, nodeB = base + rB;
        float8v accA = 0.f, accB = 0.f;
        int iA = rp_s[rA], eA = rp_s[rA + 1];
        int iB = rp_s[rB], eB = rp_s[rB + 1];
        int cA = (eA - iA) >> 3, cB = (eB - iB) >> 3;   // full 8-edge groups
        int xA = 0, xB = 0, txA = 0, txB = 0;
        int tbA = iA + (cA << 3), tbB = iB + (cB << 3);
        bool tvA = (tbA + slot < eA), tvB = (tbB + slot < eB);
        if (cA) xA = csr_src[iA + slot];
        if (cB) xB = csr_src[iB + slot];
        if (tvA) txA = csr_src[tbA + slot];
        if (tvB) txB = csr_src[tbB + slot];
        while (cA && cB) {
            half8 vA = *(const half8*)(gin + (size_t)xA * H + c8);
            half8 vB = *(const half8*)(gin + (size_t)xB * H + c8);
            iA += 8; iB += 8; --cA; --cB;
            if (cA) xA = csr_src[iA + slot];      // issued before vA/vB consumed
            if (cB) xB = csr_src[iB + slot];
#pragma unroll
            for (int k = 0; k < 8; ++k) { accA[k] += (float)vA[k]; accB[k] += (float)vB[k]; }
        }
        while (cA) {
            half8 vA = *(const half8*)(gin + (size_t)xA * H + c8);
            iA += 8; --cA;
            if (cA) xA = csr_src[iA + slot];
#pragma unroll
            for (int k = 0; k < 8; ++k) accA[k] += (float)vA[k];
        }
        while (cB) {
            half8 vB = *(const half8*)(gin + (size_t)xB * H + c8);
            iB += 8; --cB;
            if (cB) xB = csr_src[iB + slot];
#pragma unroll
            for (int k = 0; k < 8; ++k) accB[k] += (float)vB[k];
        }
        if (tvA) {
            half8 vA = *(const half8*)(gin + (size_t)txA * H + c8);
#pragma unroll
            for (int k = 0; k < 8; ++k) accA[k] += (float)vA[k];
        }
        if (tvB) {
            half8 vB = *(const half8*)(gin + (size_t)txB * H + c8);
#pragma unroll
            for (int k = 0; k < 8; ++k) accB[k] += (float)vB[k];
        }
        // two independent reduce chains, interleaved
#pragma unroll
        for (int m = 1; m <= 4; m <<= 1) {
#pragma unroll
            for (int k = 0; k < 8; ++k) {
                accA[k] += __shfl_xor(accA[k], m, 64);
                accB[k] += __shfl_xor(accB[k], m, 64);
            }
        }
        if (slot == 0) {
            float oA[8], oB[8];
            if (nodeA < n) {
                half8 sA = *(const half8*)(gin + (size_t)nodeA * H + c8);
                float dA = dv_s[rA];
#pragma unroll
                for (int k = 0; k < 8; ++k) oA[k] = (accA[k] + (float)sA[k]) * dA;
            } else {
#pragma unroll
                for (int k = 0; k < 8; ++k) oA[k] = 0.f;
            }
            if (nodeB < n) {
                half8 sB = *(const half8*)(gin + (size_t)nodeB * H + c8);
                float dB = dv_s[rB];
#pragma unroll
                for (int k = 0; k < 8; ++k) oB[k] = (accB[k] + (float)sB[k]) * dB;
            } else {
#pragma unroll
                for (int k = 0; k < 8; ++k) oB[k] = 0.f;
            }
            *(float4*)&As[rA * 68 + c8]     = make_float4(oA[0], oA[1], oA[2], oA[3]);
            *(float4*)&As[rA * 68 + c8 + 4] = make_float4(oA[4], oA[5], oA[6], oA[7]);
            *(float4*)&As[rB * 68 + c8]     = make_float4(oB[0], oB[1], oB[2], oB[3]);
            *(float4*)&As[rB * 68 + c8 + 4] = make_float4(oB[4], oB[5], oB[6], oB[7]);
        }
    }
    __syncthreads();

    // phase 2: 4x4 tile GEMM, W from global (L1-hot)
    int tx = t & 15, ty = t >> 4;
    int c0 = tx * 4;
    const float* a0 = As + (ty * 4 + 0) * 68;
    const float* a1 = As + (ty * 4 + 1) * 68;
    const float* a2 = As + (ty * 4 + 2) * 68;
    const float* a3 = As + (ty * 4 + 3) * 68;
    float4 acc0 = make_float4(0.f, 0.f, 0.f, 0.f);
    float4 acc1 = acc0, acc2 = acc0, acc3 = acc0;
#pragma unroll 16
    for (int k = 0; k < H; ++k) {
        float4 w = *(const float4*)(W + k * H + c0);
        float v0 = a0[k], v1 = a1[k], v2 = a2[k], v3 = a3[k];
        acc0.x += v0 * w.x; acc0.y += v0 * w.y; acc0.z += v0 * w.z; acc0.w += v0 * w.w;
        acc1.x += v1 * w.x; acc1.y += v1 * w.y; acc1.z += v1 * w.z; acc1.w += v1 * w.w;
        acc2.x += v2 * w.x; acc2.y += v2 * w.y; acc2.z += v2 * w.z; acc2.w += v2 * w.w;
        acc3.x += v3 * w.x; acc3.y += v3 * w.y; acc3.z += v3 * w.z; acc3.w += v3 * w.w;
    }
    float4 b = *(const float4*)(bias + c0);
    float4 accs[4] = {acc0, acc1, acc2, acc3};
#pragma unroll
    for (int rr = 0; rr < 4; ++rr) {
        int r = ty * 4 + rr;
        int row = base + r;
        if (row < n) {
            float4 o;
            o.x = fmaxf(accs[rr].x + b.x, 0.f);
            o.y = fmaxf(accs[rr].y + b.y, 0.f);
            o.z = fmaxf(accs[rr].z + b.z, 0.f);
            o.w = fmaxf(accs[rr].w + b.w, 0.f);
            if (last) {
                *(float4*)(hout + (size_t)row * H + c0) = o;
            } else {
                float d = dv_s[r];
                half4 hh;
                hh.x = (_Float16)(o.x * d);
                hh.y = (_Float16)(o.y * d);
                hh.z = (_Float16)(o.z * d);
                hh.w = (_Float16)(o.w * d);
                *(half4*)(gout + (size_t)row * H + c0) = hh;
            }
        }
    }
}

// ================= heads (lane = node) =================
__global__ void k_heads(const float* __restrict__ h,
                        const float* __restrict__ Wd1, const float* __restrict__ bd1,
                        const float* __restrict__ Wd2, const float* __restrict__ bd2,
                        const float* __restrict__ Wi1, const float* __restrict__ bi1,
                        const float* __restrict__ Wi2, const float* __restrict__ bi2,
                        float* __restrict__ out, int n) {
    __shared__ float hs[64 * 65];
    int lane = threadIdx.x;          // blockDim = 64
    int base = blockIdx.x * 64;
    for (int r = 0; r < 64; ++r) {
        int row = base + r;
        hs[r * 65 + lane] = (row < n) ? h[(size_t)row * H + lane] : 0.f;
    }
    __syncthreads();

    float accd[32], acci[32];
#pragma unroll
    for (int j = 0; j < 32; ++j) { accd[j] = bd1[j]; acci[j] = bi1[j]; }
    for (int k = 0; k < H; ++k) {
        float hk = hs[lane * 65 + k];
#pragma unroll
        for (int j = 0; j < 32; ++j) {
            accd[j] += hk * Wd1[k * 32 + j];
            acci[j] += hk * Wi1[k * 32 + j];
        }
    }
    float demand = bd2[0], inventory = bi2[0];
#pragma unroll
    for (int j = 0; j < 32; ++j) {
        demand    += fmaxf(accd[j], 0.f) * Wd2[j];
        inventory += fmaxf(acci[j], 0.f) * Wi2[j];
    }
    int node = base + lane;
    if (node < n) {
        out[node] = demand;
        out[n + node] = inventory;
    }
}

extern "C" void kernel_launch(void* const* d_in, const int* in_sizes, int n_in,
                              void* d_out, int out_size, void* d_ws, size_t ws_size,
                              hipStream_t stream) {
    const float* x   = (const float*)d_in[0];
    const int*   ei  = (const int*)  d_in[1];
    // d_in[2] = edge_attr, d_in[5] = We, d_in[6] = be : dead code in reference.
    const float* Wn  = (const float*)d_in[3];
    const float* bn  = (const float*)d_in[4];
    const float* Wc  = (const float*)d_in[7];   // [3,64,64]
    const float* bc  = (const float*)d_in[8];   // [3,64]
    const float* Wd1 = (const float*)d_in[9];
    const float* bd1 = (const float*)d_in[10];
    const float* Wd2 = (const float*)d_in[11];
    const float* bd2 = (const float*)d_in[12];
    const float* Wi1 = (const float*)d_in[13];
    const float* bi1 = (const float*)d_in[14];
    const float* Wi2 = (const float*)d_in[15];
    const float* bi2 = (const float*)d_in[16];

    const int n  = in_sizes[0] / FN;   // 100000
    const int nE = in_sizes[1] / 2;    // 1600000
    const int* src = ei;
    const int* dst = ei + nE;

    const int nbE = (nE + EPB - 1) / EPB;       // 391 scatter blocks
    const int nbB = (n + 255) >> BSHIFT;        // 391 buckets
    const int nbL = (n + 63) / 64;              // 1563

    char* w = (char*)d_ws;
    int* binned    = (int*)w;   w += (size_t)nbE * EPB * 4;
    int* csr_src   = (int*)w;   w += (size_t)nE * 4;
    int* row_ptr   = (int*)w;   w += (size_t)(n + 4) * 4;
    float* dinv    = (float*)w; w += (size_t)n * 4;
    int* lofs      = (int*)w;   w += (size_t)(nbB + 1) * nbE * 4;   // transposed [b][sb]
    int* bcounts   = (int*)w;   w += 512 * 4;
    int* bbase     = (int*)w;   w += 516 * 4;
    float* hbuf    = (float*)w; w += (size_t)n * H * 4;
    _Float16* gA   = (_Float16*)w; w += (size_t)n * H * 2;
    _Float16* gB   = (_Float16*)w; w += (size_t)n * H * 2;

    hipMemsetAsync(bcounts, 0, 512 * 4, stream);

    k_bscatter2<<<nbE, 256, 0, stream>>>(src, dst, lofs, bcounts, binned, nE, nbB, nbE);
    k_bscan2   <<<1,   512, 0, stream>>>(bcounts, bbase, nbB);
    k_bcsr2    <<<nbB, 256, 0, stream>>>(binned, lofs, bbase, row_ptr, csr_src,
                                         dinv, n, nE, nbE, nbB);

    k_enc<<<(n + 15) / 16, 256, 0, stream>>>(x, Wn, bn, dinv, gA, n);

    k_layer<<<nbL, 256, 0, stream>>>(gA, csr_src, row_ptr, dinv, Wc,
                                     bc, gB, hbuf, n, 0);
    k_layer<<<nbL, 256, 0, stream>>>(gB, csr_src, row_ptr, dinv, Wc + (size_t)H * H,
                                     bc + H, gA, hbuf, n, 0);
    k_layer<<<nbL, 256, 0, stream>>>(gA, csr_src, row_ptr, dinv, Wc + (size_t)2 * H * H,
                                     bc + 2 * H, gB, hbuf, n, 1);

    k_heads<<<(n + 63) / 64, 64, 0, stream>>>(hbuf, Wd1, bd1, Wd2, bd2,
                                              Wi1, bi1, Wi2, bi2, (float*)d_out, n);
}